// Round 2
// baseline (923.930 us; speedup 1.0000x reference)
//
#include <hip/hip_runtime.h>
#include <stdint.h>
#include <math.h>

#define NB 8
#define NN 4096
#define ND 64

__host__ __device__ __forceinline__ uint32_t rotl32(uint32_t x, uint32_t d) {
  return (x << d) | (x >> (32u - d));
}

// JAX threefry2x32: 20 rounds, rotations (13,15,26,6),(17,29,16,24)
__host__ __device__ __forceinline__ void tf2x32(uint32_t k0, uint32_t k1,
                                                uint32_t& x0, uint32_t& x1) {
  const uint32_t ks2 = k0 ^ k1 ^ 0x1BD11BDAu;
  x0 += k0; x1 += k1;
#define TF_R(r) { x0 += x1; x1 = rotl32(x1, r); x1 ^= x0; }
  TF_R(13u) TF_R(15u) TF_R(26u) TF_R(6u)
  x0 += k1;  x1 += ks2 + 1u;
  TF_R(17u) TF_R(29u) TF_R(16u) TF_R(24u)
  x0 += ks2; x1 += k0 + 2u;
  TF_R(13u) TF_R(15u) TF_R(26u) TF_R(6u)
  x0 += k0;  x1 += k1 + 3u;
  TF_R(17u) TF_R(29u) TF_R(16u) TF_R(24u)
  x0 += k1;  x1 += ks2 + 4u;
  TF_R(13u) TF_R(15u) TF_R(26u) TF_R(6u)
  x0 += ks2; x1 += k0 + 5u;
#undef TF_R
}

// gumbel = -log(-log(u)), u = uniform[tiny,1) from 32 random bits.
// Each log computed in f64 then rounded to f32 (correctly-rounded f32 log),
// keeping the reference's f32 intermediate rounding at each step.
__device__ __forceinline__ float gumbel_from_bits(uint32_t bits) {
  const float tiny = 1.1754943508222875e-38f;
  uint32_t fb = (bits >> 9) | 0x3f800000u;
  float f = __uint_as_float(fb) - 1.0f;      // [0,1)
  float u = fmaxf(tiny, f + tiny);           // floats*(1-tiny)+tiny -> f+tiny; max(tiny,.)
  float w = (float)(-log((double)u));        // -log(u), f32-rounded
  float g = (float)(-log((double)w));        // -log(w), f32-rounded
  return g;
}

// Partitionable threefry: bits for flat element e = out0 ^ out1 of block (0, e).
// One workgroup per output row (b,i): argmax_j gumbel[e=(b*NN+i)*NN+j] + w[b,j].
__global__ __launch_bounds__(256)
void cat_kernel(const float* __restrict__ weight, int* __restrict__ idx_out,
                uint32_t k0, uint32_t k1) {
  int row = blockIdx.x;               // b*NN + i, 0..32767
  int b = row >> 12;
  uint32_t base = (uint32_t)row << 12;  // row * NN
  const float* wrow = weight + b * NN;

  float best = -INFINITY; int bj = 0;
  for (int j = threadIdx.x; j < NN; j += 256) {
    uint32_t x0 = 0u, x1 = base + (uint32_t)j;
    tf2x32(k0, k1, x0, x1);
    float g = gumbel_from_bits(x0 ^ x1) + wrow[j];
    if (g > best) { best = g; bj = j; }
  }

  __shared__ float sv[256];
  __shared__ int   si[256];
  int t = threadIdx.x;
  sv[t] = best; si[t] = bj;
  __syncthreads();
  for (int s = 128; s > 0; s >>= 1) {
    if (t < s) {
      float c = sv[t + s]; int ic = si[t + s];
      if (c > sv[t] || (c == sv[t] && ic < si[t])) { sv[t] = c; si[t] = ic; }
    }
    __syncthreads();
  }
  if (t == 0) idx_out[row] = si[0];
}

// new_state[b,i,d] = state[b, idx[b,i], d] + 0.1 * sqrt(2)*erfinv(u)
// bits for flat element e of (B,N,D) = out0 ^ out1 of block (0, e) under k_noise.
// new_weight = 0 (density - stop_gradient(density) is identically zero fwd).
__global__ __launch_bounds__(256)
void sample_kernel(const float* __restrict__ state, const int* __restrict__ idx,
                   float* __restrict__ out_state, float* __restrict__ out_w,
                   uint32_t k0, uint32_t k1) {
  uint32_t e = (uint32_t)(blockIdx.x * 256 + threadIdx.x);  // 0 .. 2097151
  uint32_t x0 = 0u, x1 = e;
  tf2x32(k0, k1, x0, x1);
  uint32_t bits = x0 ^ x1;

  const float lo = -0.9999999403953552f;     // nextafter(-1, 0)
  uint32_t fb = (bits >> 9) | 0x3f800000u;
  float f = __uint_as_float(fb) - 1.0f;      // [0,1)
  float u = fmaxf(lo, fmaf(f, 2.0f, lo));    // floats*(hi-lo)+lo, hi-lo==2.0f (mul exact)
  float nz = 1.41421356237f * erfinvf(u);

  uint32_t bi = e >> 6;          // b*NN + i
  uint32_t d  = e & 63u;
  uint32_t b  = bi >> 12;
  int anc = idx[bi];
  float a = state[((size_t)b * NN + (size_t)anc) * ND + d];
  out_state[e] = fmaf(0.1f, nz, a);
  if (d == 0) out_w[bi] = 0.0f;
}

extern "C" void kernel_launch(void* const* d_in, const int* in_sizes, int n_in,
                              void* d_out, int out_size, void* d_ws, size_t ws_size,
                              hipStream_t stream) {
  const float* state  = (const float*)d_in[0];
  const float* weight = (const float*)d_in[1];
  float* out_state = (float*)d_out;
  float* out_w     = (float*)d_out + (size_t)NB * NN * ND;
  int* idx_ws = (int*)d_ws;   // NB*NN ints = 128 KiB

  // jax.random.key(42) -> [0,42]; partitionable split (foldlike):
  // child key i = full output block of threefry((0,42), counter=(0,i))
  uint32_t a0 = 0u, a1 = 0u; tf2x32(0u, 42u, a0, a1);  // counter (0,0) -> k_idx
  uint32_t b0 = 0u, b1 = 1u; tf2x32(0u, 42u, b0, b1);  // counter (0,1) -> k_noise

  hipLaunchKernelGGL(cat_kernel, dim3(NB * NN), dim3(256), 0, stream,
                     weight, idx_ws, a0, a1);
  hipLaunchKernelGGL(sample_kernel, dim3((NB * NN * ND) / 256), dim3(256), 0, stream,
                     state, idx_ws, out_state, out_w, b0, b1);
}

// Round 3
// 398.549 us; speedup vs baseline: 2.3182x; 2.3182x over previous
//
#include <hip/hip_runtime.h>
#include <stdint.h>
#include <math.h>

#define NB 8
#define NN 4096
#define ND 64

__host__ __device__ __forceinline__ uint32_t rotl32(uint32_t x, uint32_t d) {
  return (x << d) | (x >> (32u - d));
}

// JAX threefry2x32: 20 rounds, rotations (13,15,26,6),(17,29,16,24)
__host__ __device__ __forceinline__ void tf2x32(uint32_t k0, uint32_t k1,
                                                uint32_t& x0, uint32_t& x1) {
  const uint32_t ks2 = k0 ^ k1 ^ 0x1BD11BDAu;
  x0 += k0; x1 += k1;
#define TF_R(r) { x0 += x1; x1 = rotl32(x1, r); x1 ^= x0; }
  TF_R(13u) TF_R(15u) TF_R(26u) TF_R(6u)
  x0 += k1;  x1 += ks2 + 1u;
  TF_R(17u) TF_R(29u) TF_R(16u) TF_R(24u)
  x0 += ks2; x1 += k0 + 2u;
  TF_R(13u) TF_R(15u) TF_R(26u) TF_R(6u)
  x0 += k0;  x1 += k1 + 3u;
  TF_R(17u) TF_R(29u) TF_R(16u) TF_R(24u)
  x0 += k1;  x1 += ks2 + 4u;
  TF_R(13u) TF_R(15u) TF_R(26u) TF_R(6u)
  x0 += ks2; x1 += k0 + 5u;
#undef TF_R
}

// uniform[tiny,1) from 32 random bits (partitionable threefry: bits = out0^out1)
__device__ __forceinline__ float unif_from_bits(uint32_t bits) {
  const float tiny = 1.1754943508222875e-38f;
  uint32_t fb = (bits >> 9) | 0x3f800000u;
  float f = __uint_as_float(fb) - 1.0f;      // [0,1)
  return fmaxf(tiny, f + tiny);
}

// Exact (f64-rounded-to-f32) gumbel, identical to the R2 kernel that passed.
__device__ __forceinline__ float gumbel_exact(uint32_t bits) {
  float u = unif_from_bits(bits);
  float w = (float)(-log((double)u));        // -log(u), f32-rounded
  float g = (float)(-log((double)w));        // -log(w), f32-rounded
  return g;
}

// One workgroup per output row (b,i).
// Phase 1: approximate a_j = (-log u_j) * exp(-w_j) with hw log/exp; track
//          per-thread top-2 minima. argmin a_j == argmax gumbel_j + w_j.
// Phase 2: exact re-evaluation (R2 semantics: f64 logs, f32 g+w key,
//          first-index tie-break) of candidates within 0.2% of the approx min.
__global__ __launch_bounds__(256)
void cat_kernel(const float* __restrict__ weight, int* __restrict__ idx_out,
                uint32_t k0, uint32_t k1) {
  int row = blockIdx.x;               // b*NN + i, 0..32767
  int b = row >> 12;
  uint32_t base = (uint32_t)row << 12;  // row * NN
  const float* wrow = weight + (b << 12);

  float v1 = INFINITY, v2 = INFINITY;
  int i1 = 0, i2 = 0;
  for (int j = threadIdx.x; j < NN; j += 256) {
    uint32_t x0 = 0u, x1 = base + (uint32_t)j;
    tf2x32(k0, k1, x0, x1);
    float u = unif_from_bits(x0 ^ x1);
    float E = -__logf(u);                 // hw v_log_f32, ~1-2 ulp
    float a = E * __expf(-wrow[j]);       // hw v_exp_f32
    if (a < v2) {
      if (a < v1) { v2 = v1; i2 = i1; v1 = a; i1 = j; }
      else        { v2 = a;  i2 = j; }
    }
  }

  // block min of v1
  __shared__ float red[256];
  int t = threadIdx.x;
  red[t] = v1;
  __syncthreads();
  for (int s = 128; s > 0; s >>= 1) {
    if (t < s) red[t] = fminf(red[t], red[t + s]);
    __syncthreads();
  }
  float thr = red[0] * 1.002f;   // margin >> hw log/exp error (incl. u~1 cancellation)

  __shared__ int cnt;
  __shared__ float ckey[64];
  __shared__ int cidx[64];
  if (t == 0) cnt = 0;
  __syncthreads();

  #pragma unroll
  for (int c = 0; c < 2; ++c) {
    float v = c ? v2 : v1;
    int j   = c ? i2 : i1;
    if (v <= thr) {
      uint32_t x0 = 0u, x1 = base + (uint32_t)j;
      tf2x32(k0, k1, x0, x1);
      float key = gumbel_exact(x0 ^ x1) + wrow[j];
      int slot = atomicAdd(&cnt, 1);
      if (slot < 64) { ckey[slot] = key; cidx[slot] = j; }
    }
  }
  __syncthreads();
  if (t == 0) {
    int n = cnt < 64 ? cnt : 64;
    float bk = -INFINITY; int bj = 0x7fffffff;
    for (int q = 0; q < n; ++q) {
      float kq = ckey[q]; int jq = cidx[q];
      if (kq > bk || (kq == bk && jq < bj)) { bk = kq; bj = jq; }
    }
    idx_out[row] = bj;
  }
}

// new_state[b,i,d] = state[b, idx[b,i], d] + 0.1 * sqrt(2)*erfinv(u)
// new_weight = 0 (density - stop_gradient(density) is identically zero fwd).
__global__ __launch_bounds__(256)
void sample_kernel(const float* __restrict__ state, const int* __restrict__ idx,
                   float* __restrict__ out_state, float* __restrict__ out_w,
                   uint32_t k0, uint32_t k1) {
  uint32_t e = (uint32_t)(blockIdx.x * 256 + threadIdx.x);  // 0 .. 2097151
  uint32_t x0 = 0u, x1 = e;
  tf2x32(k0, k1, x0, x1);
  uint32_t bits = x0 ^ x1;

  const float lo = -0.9999999403953552f;     // nextafter(-1, 0)
  uint32_t fb = (bits >> 9) | 0x3f800000u;
  float f = __uint_as_float(fb) - 1.0f;      // [0,1)
  float u = fmaxf(lo, fmaf(f, 2.0f, lo));    // f*(hi-lo)+lo, hi-lo==2.0f (exact mul)
  float nz = 1.41421356237f * erfinvf(u);

  uint32_t bi = e >> 6;          // b*NN + i
  uint32_t d  = e & 63u;
  uint32_t b  = bi >> 12;
  int anc = idx[bi];
  float a = state[((size_t)b * NN + (size_t)anc) * ND + d];
  out_state[e] = fmaf(0.1f, nz, a);
  if (d == 0) out_w[bi] = 0.0f;
}

extern "C" void kernel_launch(void* const* d_in, const int* in_sizes, int n_in,
                              void* d_out, int out_size, void* d_ws, size_t ws_size,
                              hipStream_t stream) {
  const float* state  = (const float*)d_in[0];
  const float* weight = (const float*)d_in[1];
  float* out_state = (float*)d_out;
  float* out_w     = (float*)d_out + (size_t)NB * NN * ND;
  int* idx_ws = (int*)d_ws;   // NB*NN ints = 128 KiB

  // jax.random.key(42) -> [0,42]; partitionable split (foldlike):
  // child key i = full output block of threefry((0,42), counter=(0,i))
  uint32_t a0 = 0u, a1 = 0u; tf2x32(0u, 42u, a0, a1);  // counter (0,0) -> k_idx
  uint32_t b0 = 0u, b1 = 1u; tf2x32(0u, 42u, b0, b1);  // counter (0,1) -> k_noise

  hipLaunchKernelGGL(cat_kernel, dim3(NB * NN), dim3(256), 0, stream,
                     weight, idx_ws, a0, a1);
  hipLaunchKernelGGL(sample_kernel, dim3((NB * NN * ND) / 256), dim3(256), 0, stream,
                     state, idx_ws, out_state, out_w, b0, b1);
}

// Round 4
// 387.171 us; speedup vs baseline: 2.3864x; 1.0294x over previous
//
#include <hip/hip_runtime.h>
#include <stdint.h>
#include <math.h>

#define NB 8
#define NN 4096
#define ND 64

__host__ __device__ __forceinline__ uint32_t rotl32(uint32_t x, uint32_t d) {
  return (x << d) | (x >> (32u - d));
}

// JAX threefry2x32: 20 rounds, rotations (13,15,26,6),(17,29,16,24)
__host__ __device__ __forceinline__ void tf2x32(uint32_t k0, uint32_t k1,
                                                uint32_t& x0, uint32_t& x1) {
  const uint32_t ks2 = k0 ^ k1 ^ 0x1BD11BDAu;
  x0 += k0; x1 += k1;
#define TF_R(r) { x0 += x1; x1 = rotl32(x1, r); x1 ^= x0; }
  TF_R(13u) TF_R(15u) TF_R(26u) TF_R(6u)
  x0 += k1;  x1 += ks2 + 1u;
  TF_R(17u) TF_R(29u) TF_R(16u) TF_R(24u)
  x0 += ks2; x1 += k0 + 2u;
  TF_R(13u) TF_R(15u) TF_R(26u) TF_R(6u)
  x0 += k0;  x1 += k1 + 3u;
  TF_R(17u) TF_R(29u) TF_R(16u) TF_R(24u)
  x0 += k1;  x1 += ks2 + 4u;
  TF_R(13u) TF_R(15u) TF_R(26u) TF_R(6u)
  x0 += ks2; x1 += k0 + 5u;
#undef TF_R
}

// uniform[tiny,1) from 32 random bits (partitionable threefry: bits = out0^out1)
__device__ __forceinline__ float unif_from_bits(uint32_t bits) {
  const float tiny = 1.1754943508222875e-38f;
  uint32_t fb = (bits >> 9) | 0x3f800000u;
  float f = __uint_as_float(fb) - 1.0f;      // [0,1)
  return fmaxf(tiny, f + tiny);
}

// Exact (f64-rounded-to-f32) gumbel — must match the passing R2/R3 semantics.
__device__ __forceinline__ float gumbel_exact(uint32_t bits) {
  float u = unif_from_bits(bits);
  float w = (float)(-log((double)u));        // -log(u), f32-rounded
  float g = (float)(-log((double)w));        // -log(w), f32-rounded
  return g;
}

// c[b,j] = exp(-w[b,j])  (hw exp; only used for approximate phase-1 keys)
__global__ __launch_bounds__(256)
void expw_kernel(const float* __restrict__ weight, float* __restrict__ cexp) {
  int i = blockIdx.x * 256 + threadIdx.x;    // 0 .. 32767
  cexp[i] = __expf(-weight[i]);
}

// One 128-thread block per output row (b,i), 32 elements/thread.
// Phase 1: a_j = (-log u_j) * c_j with hw log; per-thread top-2 minima.
//          argmin a_j == argmax gumbel_j + w_j (monotone transform).
// Phase 2: exact re-eval (f64 logs, f32 g+w key, first-index tie-break) of
//          candidates within 0.2% of the approx min (>> hw log error).
__global__ __launch_bounds__(128)
void cat_kernel(const float* __restrict__ weight, const float* __restrict__ cexp,
                int* __restrict__ idx_out, uint32_t k0, uint32_t k1) {
  int row = blockIdx.x;                 // b*NN + i, 0..32767
  int b = row >> 12;
  uint32_t base = (uint32_t)row << 12;  // row * NN
  const float* crow = cexp + (b << 12);
  const float* wrow = weight + (b << 12);
  int t = threadIdx.x;

  float v1 = INFINITY, v2 = INFINITY;
  int i1 = 0, i2 = 0;
  #pragma unroll 4
  for (int j = t; j < NN; j += 128) {
    uint32_t x0 = 0u, x1 = base + (uint32_t)j;
    tf2x32(k0, k1, x0, x1);
    float u = unif_from_bits(x0 ^ x1);
    float a = -__logf(u) * crow[j];          // v_log_f32 + 2 mul
    if (a < v2) {
      if (a < v1) { v2 = v1; i2 = i1; v1 = a; i1 = j; }
      else        { v2 = a;  i2 = j; }
    }
  }

  // wave-level min of v1, then cross-wave via 2-slot LDS
  float m = v1;
  #pragma unroll
  for (int off = 1; off < 64; off <<= 1) m = fminf(m, __shfl_xor(m, off));
  __shared__ float wmin[2];
  __shared__ int cnt;
  __shared__ float ckey[16];
  __shared__ int cidx[16];
  int lane = t & 63, wid = t >> 6;
  if (t == 0) cnt = 0;
  if (lane == 0) wmin[wid] = m;
  __syncthreads();
  float thr = fminf(wmin[0], wmin[1]) * 1.002f;

  #pragma unroll
  for (int c = 0; c < 2; ++c) {
    float v = c ? v2 : v1;
    int j   = c ? i2 : i1;
    if (v <= thr) {
      uint32_t x0 = 0u, x1 = base + (uint32_t)j;
      tf2x32(k0, k1, x0, x1);
      float key = gumbel_exact(x0 ^ x1) + wrow[j];
      int slot = atomicAdd(&cnt, 1);
      if (slot < 16) { ckey[slot] = key; cidx[slot] = j; }
    }
  }
  __syncthreads();
  if (t == 0) {
    int n = cnt < 16 ? cnt : 16;
    float bk = -INFINITY; int bj = 0x7fffffff;
    for (int q = 0; q < n; ++q) {
      float kq = ckey[q]; int jq = cidx[q];
      if (kq > bk || (kq == bk && jq < bj)) { bk = kq; bj = jq; }
    }
    idx_out[row] = bj;
  }
}

// new_state[b,i,d] = state[b, idx[b,i], d] + 0.1 * sqrt(2)*erfinv(u)
// new_weight = 0 (density - stop_gradient(density) is identically zero fwd).
__global__ __launch_bounds__(256)
void sample_kernel(const float* __restrict__ state, const int* __restrict__ idx,
                   float* __restrict__ out_state, float* __restrict__ out_w,
                   uint32_t k0, uint32_t k1) {
  uint32_t e = (uint32_t)(blockIdx.x * 256 + threadIdx.x);  // 0 .. 2097151
  uint32_t x0 = 0u, x1 = e;
  tf2x32(k0, k1, x0, x1);
  uint32_t bits = x0 ^ x1;

  const float lo = -0.9999999403953552f;     // nextafter(-1, 0)
  uint32_t fb = (bits >> 9) | 0x3f800000u;
  float f = __uint_as_float(fb) - 1.0f;      // [0,1)
  float u = fmaxf(lo, fmaf(f, 2.0f, lo));    // f*(hi-lo)+lo, hi-lo==2.0f (exact mul)
  float nz = 1.41421356237f * erfinvf(u);

  uint32_t bi = e >> 6;          // b*NN + i
  uint32_t d  = e & 63u;
  uint32_t b  = bi >> 12;
  int anc = idx[bi];
  float a = state[((size_t)b * NN + (size_t)anc) * ND + d];
  out_state[e] = fmaf(0.1f, nz, a);
  if (d == 0) out_w[bi] = 0.0f;
}

extern "C" void kernel_launch(void* const* d_in, const int* in_sizes, int n_in,
                              void* d_out, int out_size, void* d_ws, size_t ws_size,
                              hipStream_t stream) {
  const float* state  = (const float*)d_in[0];
  const float* weight = (const float*)d_in[1];
  float* out_state = (float*)d_out;
  float* out_w     = (float*)d_out + (size_t)NB * NN * ND;
  int*   idx_ws = (int*)d_ws;                          // 32768 ints  = 128 KiB
  float* cexp   = (float*)d_ws + NB * NN;              // 32768 float = 128 KiB

  // jax.random.key(42) -> [0,42]; partitionable split (foldlike):
  // child key i = full output block of threefry((0,42), counter=(0,i))
  uint32_t a0 = 0u, a1 = 0u; tf2x32(0u, 42u, a0, a1);  // counter (0,0) -> k_idx
  uint32_t b0 = 0u, b1 = 1u; tf2x32(0u, 42u, b0, b1);  // counter (0,1) -> k_noise

  hipLaunchKernelGGL(expw_kernel, dim3(NB * NN / 256), dim3(256), 0, stream,
                     weight, cexp);
  hipLaunchKernelGGL(cat_kernel, dim3(NB * NN), dim3(128), 0, stream,
                     weight, cexp, idx_ws, a0, a1);
  hipLaunchKernelGGL(sample_kernel, dim3((NB * NN * ND) / 256), dim3(256), 0, stream,
                     state, idx_ws, out_state, out_w, b0, b1);
}

// Round 5
// 297.567 us; speedup vs baseline: 3.1049x; 1.3011x over previous
//
#include <hip/hip_runtime.h>
#include <stdint.h>
#include <math.h>

#define NB 8
#define NN 4096
#define ND 64

__host__ __device__ __forceinline__ uint32_t rotl32(uint32_t x, uint32_t d) {
#ifdef __HIP_DEVICE_COMPILE__
  return __builtin_amdgcn_alignbit(x, x, 32u - d);   // v_alignbit_b32: 1 inst
#else
  return (x << d) | (x >> (32u - d));
#endif
}

// JAX threefry2x32: 20 rounds, rotations (13,15,26,6),(17,29,16,24)
__host__ __device__ __forceinline__ void tf2x32(uint32_t k0, uint32_t k1,
                                                uint32_t& x0, uint32_t& x1) {
  const uint32_t ks2 = k0 ^ k1 ^ 0x1BD11BDAu;
  x0 += k0; x1 += k1;
#define TF_R(r) { x0 += x1; x1 = rotl32(x1, r); x1 ^= x0; }
  TF_R(13u) TF_R(15u) TF_R(26u) TF_R(6u)
  x0 += k1;  x1 += ks2 + 1u;
  TF_R(17u) TF_R(29u) TF_R(16u) TF_R(24u)
  x0 += ks2; x1 += k0 + 2u;
  TF_R(13u) TF_R(15u) TF_R(26u) TF_R(6u)
  x0 += k0;  x1 += k1 + 3u;
  TF_R(17u) TF_R(29u) TF_R(16u) TF_R(24u)
  x0 += k1;  x1 += ks2 + 4u;
  TF_R(13u) TF_R(15u) TF_R(26u) TF_R(6u)
  x0 += ks2; x1 += k0 + 5u;
#undef TF_R
}

// uniform[tiny,1) from 32 random bits (partitionable threefry: bits = out0^out1)
__device__ __forceinline__ float unif_from_bits(uint32_t bits) {
  const float tiny = 1.1754943508222875e-38f;
  uint32_t fb = (bits >> 9) | 0x3f800000u;
  float f = __uint_as_float(fb) - 1.0f;      // [0,1)
  return fmaxf(tiny, f + tiny);
}

// Exact (f64-rounded-to-f32) gumbel — must match the passing R2-R4 semantics.
__device__ __forceinline__ float gumbel_exact(uint32_t bits) {
  float u = unif_from_bits(bits);
  float w = (float)(-log((double)u));        // -log(u), f32-rounded
  float g = (float)(-log((double)w));        // -log(w), f32-rounded
  return g;
}

// c2[b,j] = -ln2 * exp(-w[b,j])  (screen-key table; sign folds the log2->-log
// conversion so the screen is a = log2(f) * c2 = (-log f) * exp(-w) > 0)
__global__ __launch_bounds__(256)
void expw_kernel(const float* __restrict__ weight, float* __restrict__ c2) {
  int i = blockIdx.x * 256 + threadIdx.x;    // 0 .. 32767
  c2[i] = -0.69314718055994530942f * __expf(-weight[i]);
}

// One 128-thread block per output row (b,i), 32 elements/thread.
// Phase 1: a_j = log2(f_j) * c2_j with hw v_log_f32; per-thread top-2 minima.
//          argmin a_j == argmax gumbel_j + w_j (monotone transform).
//          f==0 gives a=+inf (excluded; exact E=87.3 can never be the row min).
// Phase 2: exact re-eval (f64 logs, f32 g+w key, first-index tie-break) of
//          candidates within 0.2% of the approx min (>> hw log error).
__global__ __launch_bounds__(128)
void cat_kernel(const float* __restrict__ weight, const float* __restrict__ c2,
                int* __restrict__ idx_out, uint32_t k0, uint32_t k1) {
  int row = blockIdx.x;                 // b*NN + i, 0..32767
  int b = row >> 12;
  uint32_t base = (uint32_t)row << 12;  // row * NN
  const float* crow = c2 + (b << 12);
  const float* wrow = weight + (b << 12);
  int t = threadIdx.x;

  float v1 = INFINITY, v2 = INFINITY;
  int i1 = 0, i2 = 0;
  #pragma unroll 8
  for (int j = t; j < NN; j += 128) {
    uint32_t x0 = 0u, x1 = base + (uint32_t)j;
    tf2x32(k0, k1, x0, x1);
    uint32_t bits = x0 ^ x1;
    float f = __uint_as_float((bits >> 9) | 0x3f800000u) - 1.0f;  // [0,1)
    float a = __log2f(f) * crow[j];     // v_log_f32 + v_mul
    if (a < v2) {
      if (a < v1) { v2 = v1; i2 = i1; v1 = a; i1 = j; }
      else        { v2 = a;  i2 = j; }
    }
  }

  // wave-level min of v1, then cross-wave via 2-slot LDS
  float m = v1;
  #pragma unroll
  for (int off = 1; off < 64; off <<= 1) m = fminf(m, __shfl_xor(m, off));
  __shared__ float wmin[2];
  __shared__ int cnt;
  __shared__ float ckey[16];
  __shared__ int cidx[16];
  int lane = t & 63, wid = t >> 6;
  if (t == 0) cnt = 0;
  if (lane == 0) wmin[wid] = m;
  __syncthreads();
  float thr = fminf(wmin[0], wmin[1]) * 1.002f;

  #pragma unroll
  for (int c = 0; c < 2; ++c) {
    float v = c ? v2 : v1;
    int j   = c ? i2 : i1;
    if (v <= thr) {
      uint32_t x0 = 0u, x1 = base + (uint32_t)j;
      tf2x32(k0, k1, x0, x1);
      float key = gumbel_exact(x0 ^ x1) + wrow[j];
      int slot = atomicAdd(&cnt, 1);
      if (slot < 16) { ckey[slot] = key; cidx[slot] = j; }
    }
  }
  __syncthreads();
  if (t == 0) {
    int n = cnt < 16 ? cnt : 16;
    float bk = -INFINITY; int bj = 0x7fffffff;
    for (int q = 0; q < n; ++q) {
      float kq = ckey[q]; int jq = cidx[q];
      if (kq > bk || (kq == bk && jq < bj)) { bk = kq; bj = jq; }
    }
    idx_out[row] = bj;
  }
}

// new_state[b,i,d] = state[b, idx[b,i], d] + 0.1 * sqrt(2)*erfinv(u)
// new_weight = 0 (density - stop_gradient(density) is identically zero fwd).
__global__ __launch_bounds__(256)
void sample_kernel(const float* __restrict__ state, const int* __restrict__ idx,
                   float* __restrict__ out_state, float* __restrict__ out_w,
                   uint32_t k0, uint32_t k1) {
  uint32_t e = (uint32_t)(blockIdx.x * 256 + threadIdx.x);  // 0 .. 2097151
  uint32_t x0 = 0u, x1 = e;
  tf2x32(k0, k1, x0, x1);
  uint32_t bits = x0 ^ x1;

  const float lo = -0.9999999403953552f;     // nextafter(-1, 0)
  uint32_t fb = (bits >> 9) | 0x3f800000u;
  float f = __uint_as_float(fb) - 1.0f;      // [0,1)
  float u = fmaxf(lo, fmaf(f, 2.0f, lo));    // f*(hi-lo)+lo, hi-lo==2.0f (exact mul)
  float nz = 1.41421356237f * erfinvf(u);

  uint32_t bi = e >> 6;          // b*NN + i
  uint32_t d  = e & 63u;
  uint32_t b  = bi >> 12;
  int anc = idx[bi];
  float a = state[((size_t)b * NN + (size_t)anc) * ND + d];
  out_state[e] = fmaf(0.1f, nz, a);
  if (d == 0) out_w[bi] = 0.0f;
}

extern "C" void kernel_launch(void* const* d_in, const int* in_sizes, int n_in,
                              void* d_out, int out_size, void* d_ws, size_t ws_size,
                              hipStream_t stream) {
  const float* state  = (const float*)d_in[0];
  const float* weight = (const float*)d_in[1];
  float* out_state = (float*)d_out;
  float* out_w     = (float*)d_out + (size_t)NB * NN * ND;
  int*   idx_ws = (int*)d_ws;                          // 32768 ints  = 128 KiB
  float* c2     = (float*)d_ws + NB * NN;              // 32768 float = 128 KiB

  // jax.random.key(42) -> [0,42]; partitionable split (foldlike):
  // child key i = full output block of threefry((0,42), counter=(0,i))
  uint32_t a0 = 0u, a1 = 0u; tf2x32(0u, 42u, a0, a1);  // counter (0,0) -> k_idx
  uint32_t b0 = 0u, b1 = 1u; tf2x32(0u, 42u, b0, b1);  // counter (0,1) -> k_noise

  hipLaunchKernelGGL(expw_kernel, dim3(NB * NN / 256), dim3(256), 0, stream,
                     weight, c2);
  hipLaunchKernelGGL(cat_kernel, dim3(NB * NN), dim3(128), 0, stream,
                     weight, c2, idx_ws, a0, a1);
  hipLaunchKernelGGL(sample_kernel, dim3((NB * NN * ND) / 256), dim3(256), 0, stream,
                     state, idx_ws, out_state, out_w, b0, b1);
}